// Round 1
// baseline (496.205 us; speedup 1.0000x reference)
//
#include <hip/hip_runtime.h>
#include <stdint.h>

// LinearAttention fused: qkv GEMM + dual softmax + linear attention + Wout GEMM + LayerNorm2d
// Shapes: b=32, c=128, n=64*64=4096, heads=4, dim_head=32.
// All GEMMs via v_mfma_f32_16x16x32_bf16 (fp32 accum). Softmaxes computed without
// max-subtraction (qkv values ~N(0,1), exp range safe in fp32).

constexpr int B_  = 32;
constexpr int C_  = 128;
constexpr int N_  = 4096;
constexpr int H_  = 4;
constexpr int DH_ = 32;
constexpr int O3_ = 384;   // 3*128 qkv rows

using short8  = __attribute__((ext_vector_type(8))) short;
using short4v = __attribute__((ext_vector_type(4))) short;
using float4v = __attribute__((ext_vector_type(4))) float;

__device__ __forceinline__ unsigned short bf16_rne(float f) {
    union { float f; uint32_t u; } v; v.f = f;
    uint32_t u = v.u;
    u += 0x7FFFu + ((u >> 16) & 1u);   // round-to-nearest-even
    return (unsigned short)(u >> 16);
}
__device__ __forceinline__ float bf2f(unsigned short h) {
    union { uint32_t u; float f; } v; v.u = ((uint32_t)h) << 16; return v.f;
}

// workspace layout (bytes)
constexpr size_t OFF_WQ  = 0;          // Wqkv bf16: 384*128*2 = 98304
constexpr size_t OFF_WO  = 98304;      // Wout bf16: 128*128*2 = 32768
constexpr size_t OFF_S   = 131072;     // k-softmax denominators [b][h*32+d] f32: 16384
constexpr size_t OFF_CTX = 147456;     // context raw [b][h][d][e] f32: 524288
constexpr size_t OFF_QSM = 671744;     // q-softmax bf16 [b][n][h*32+d]: 33554432
// total 34,226,176 bytes

__global__ __launch_bounds__(256) void k0_prep(const float* __restrict__ Wqkv,
                                               const float* __restrict__ Wout,
                                               unsigned short* __restrict__ wq,
                                               unsigned short* __restrict__ wo,
                                               float* __restrict__ S,
                                               float* __restrict__ ctx) {
    int t = blockIdx.x * 256 + threadIdx.x;      // grid = 512*256 = 131072 exactly
    if (t < O3_ * C_) wq[t] = bf16_rne(Wqkv[t]);
    if (t < C_ * C_)  wo[t] = bf16_rne(Wout[t]);
    if (t < B_ * H_ * DH_) S[t] = 0.0f;
    ctx[t] = 0.0f;                                // 32*4*32*32 = 131072 floats
}

// K1: per (b, 64-wide n-tile): qkv = Wqkv @ x_tile, q-softmax -> qsm (global),
// exp(k), v -> LDS, context partial = expk @ v^T (K = n) -> atomicAdd, S row sums.
__global__ __launch_bounds__(512) void k1_qkv(const float* __restrict__ x,
                                              const unsigned short* __restrict__ wq,
                                              unsigned short* __restrict__ qsm,
                                              float* __restrict__ ctx,
                                              float* __restrict__ S) {
    __shared__ __align__(16) unsigned short xs[64 * 136];    // [n][c], stride 136 (16B aligned, 2-way banks)
    __shared__ __align__(16) unsigned short ek[128 * 72];    // [h*32+d][n], stride 72
    __shared__ __align__(16) unsigned short vsh[128 * 72];   // [h*32+e][n]

    const int b  = blockIdx.y;
    const int n0 = blockIdx.x * 64;
    const int tid = threadIdx.x;

    {   // stage x (fp32 global, coalesced along n) -> bf16 LDS [n][c]
        const int nl = tid & 63;
        const int cg = tid >> 6;                 // 8 groups of 16 c
        const float* xp = x + ((size_t)b * C_ + (size_t)cg * 16) * N_ + n0 + nl;
        unsigned short* dst = &xs[nl * 136 + cg * 16];
        #pragma unroll
        for (int i = 0; i < 2; i++) {
            short8 v8;
            #pragma unroll
            for (int j = 0; j < 8; j++)
                v8[j] = (short)bf16_rne(xp[(size_t)(i * 8 + j) * N_]);
            *(short8*)(dst + i * 8) = v8;        // 16B aligned: n*272 + cg*32 + i*16
        }
    }
    __syncthreads();

    const int lane = tid & 63;
    const int wv   = tid >> 6;                   // 0..7
    const int l15  = lane & 15;
    const int quad = lane >> 4;
    const int cw   = wv & 3;                     // n col-tile within the 64
    const int ncol = cw * 16 + l15;

    // B-frags (x) loaded once, reused for all 24 row-tiles: B[k=c][col=n]
    short8 bfx[4];
    #pragma unroll
    for (int kk = 0; kk < 4; kk++)
        bfx[kk] = *(const short8*)&xs[ncol * 136 + kk * 32 + quad * 8];

    const int rp0 = (wv >> 2) * 6;               // waves 0-3: row-pairs 0..5; 4-7: 6..11
    for (int rp = rp0; rp < rp0 + 6; rp++) {
        const unsigned short* wqp = wq + (rp * 32 + l15) * C_ + quad * 8;
        float4v acc0 = {0.f, 0.f, 0.f, 0.f};
        float4v acc1 = {0.f, 0.f, 0.f, 0.f};
        #pragma unroll
        for (int kk = 0; kk < 4; kk++) {
            short8 a0 = *(const short8*)(wqp + kk * 32);
            short8 a1 = *(const short8*)(wqp + 16 * C_ + kk * 32);
            acc0 = __builtin_amdgcn_mfma_f32_16x16x32_bf16(a0, bfx[kk], acc0, 0, 0, 0);
            acc1 = __builtin_amdgcn_mfma_f32_16x16x32_bf16(a1, bfx[kk], acc1, 0, 0, 0);
        }
        // C/D layout: col = l15 (n), row = quad*4 + r (acc0: d 0..15, acc1: d 16..31)
        if (rp < 4) {
            // q rows, head h = rp: softmax over d (32) per column
            float e0[4], e1[4];
            float z = 0.f;
            #pragma unroll
            for (int r = 0; r < 4; r++) {
                e0[r] = __expf(acc0[r]); e1[r] = __expf(acc1[r]);
                z += e0[r] + e1[r];
            }
            z += __shfl_xor(z, 16, 64);
            z += __shfl_xor(z, 32, 64);
            const float iz = 1.0f / z;
            unsigned short* qp = qsm + ((size_t)b * N_ + n0 + ncol) * C_ + rp * 32 + quad * 4;
            short4v s0, s1;
            #pragma unroll
            for (int r = 0; r < 4; r++) {
                s0[r] = (short)bf16_rne(e0[r] * iz);
                s1[r] = (short)bf16_rne(e1[r] * iz);
            }
            *(short4v*)qp = s0;                  // d = quad*4..+3
            *(short4v*)(qp + 16) = s1;           // d = 16+quad*4..+3
        } else if (rp < 8) {
            // k rows, head h = rp-4: exp -> LDS [h*32+d][n]
            const int row0 = (rp - 4) * 32 + quad * 4;
            #pragma unroll
            for (int r = 0; r < 4; r++) {
                ek[(row0 + r) * 72 + ncol]      = bf16_rne(__expf(acc0[r]));
                ek[(row0 + 16 + r) * 72 + ncol] = bf16_rne(__expf(acc1[r]));
            }
        } else {
            // v rows, head h = rp-8 -> LDS [h*32+e][n]
            const int row0 = (rp - 8) * 32 + quad * 4;
            #pragma unroll
            for (int r = 0; r < 4; r++) {
                vsh[(row0 + r) * 72 + ncol]      = bf16_rne(acc0[r]);
                vsh[(row0 + 16 + r) * 72 + ncol] = bf16_rne(acc1[r]);
            }
        }
    }
    __syncthreads();

    // context partial: ctx[d][e] += sum_n expk[d][n] * v[e][n]  (MFMA, K = n = 64)
    #pragma unroll
    for (int i = 0; i < 2; i++) {
        const int t = wv * 2 + i;                // 16 tiles: (h, d-tile, e-tile)
        const int h = t >> 2, dt = (t >> 1) & 1, et = t & 1;
        float4v c4 = {0.f, 0.f, 0.f, 0.f};
        const unsigned short* ap = &ek[(h * 32 + dt * 16 + l15) * 72 + quad * 8];
        const unsigned short* bp = &vsh[(h * 32 + et * 16 + l15) * 72 + quad * 8];
        #pragma unroll
        for (int kk = 0; kk < 2; kk++) {
            short8 a  = *(const short8*)(ap + kk * 32);
            short8 bb = *(const short8*)(bp + kk * 32);
            c4 = __builtin_amdgcn_mfma_f32_16x16x32_bf16(a, bb, c4, 0, 0, 0);
        }
        float* cp = ctx + (((size_t)b * H_ + h) * 32 + dt * 16 + quad * 4) * 32 + et * 16 + l15;
        #pragma unroll
        for (int r = 0; r < 4; r++) atomicAdd(cp + r * 32, c4[r]);
    }

    {   // S partial sums (same bf16 values the context MFMA consumed -> consistent)
        const int row = tid >> 2;                // 0..127 = h*32+d
        const int sub = tid & 3;
        const unsigned short* ep = &ek[row * 72 + sub * 16];
        float s = 0.f;
        #pragma unroll
        for (int j = 0; j < 16; j++) s += bf2f(ep[j]);
        atomicAdd(&S[b * 128 + row], s);
    }
}

// K3: out2 = ctx^T @ qsm per head (K=32), y = Wout @ out2 + bout (K=128), LayerNorm over c, store.
__global__ __launch_bounds__(256) void k3_out(const unsigned short* __restrict__ qsm,
                                              const float* __restrict__ ctx,
                                              const float* __restrict__ S,
                                              const unsigned short* __restrict__ wo,
                                              const float* __restrict__ bout,
                                              const float* __restrict__ lnw,
                                              const float* __restrict__ lnb,
                                              float* __restrict__ out) {
    __shared__ __align__(16) unsigned short ctxA[128 * 40];  // [h*32+e][d], stride 40
    __shared__ __align__(16) unsigned short o2[64 * 136];    // [n][h*32+e], stride 136

    const int b  = blockIdx.y;
    const int n0 = blockIdx.x * 64;
    const int tid = threadIdx.x;

    #pragma unroll
    for (int i = 0; i < 16; i++) {               // load ctx, scale by 1/S, transpose
        const int ei = i * 256 + tid;            // [h][d][e] flat
        const int h = ei >> 10, d = (ei >> 5) & 31, e = ei & 31;
        const float val = ctx[(size_t)b * 4096 + ei] / S[b * 128 + h * 32 + d];
        ctxA[(h * 32 + e) * 40 + d] = bf16_rne(val);
    }
    __syncthreads();

    const int lane = tid & 63, wv = tid >> 6, l15 = lane & 15, quad = lane >> 4;
    const int nl = wv * 16 + l15;
    const size_t n = (size_t)n0 + nl;

    const float4v zero = {0.f, 0.f, 0.f, 0.f};
    #pragma unroll
    for (int h = 0; h < 4; h++) {
        // B-frag: qsm[d][n] with d contiguous in global layout [b][n][h*32+d]
        short8 bq = *(const short8*)(qsm + ((size_t)b * N_ + n) * C_ + h * 32 + quad * 8);
        #pragma unroll
        for (int et = 0; et < 2; et++) {
            short8 a = *(const short8*)&ctxA[(h * 32 + et * 16 + l15) * 40 + quad * 8];
            float4v c4 = __builtin_amdgcn_mfma_f32_16x16x32_bf16(a, bq, zero, 0, 0, 0);
            short4v s4;
            #pragma unroll
            for (int r = 0; r < 4; r++) s4[r] = (short)bf16_rne(c4[r]);
            *(short4v*)&o2[nl * 136 + h * 32 + et * 16 + quad * 4] = s4;
        }
    }
    __syncthreads();

    short8 bfr[4];                               // B-frags (out2) reused across 8 o-tiles
    #pragma unroll
    for (int kk = 0; kk < 4; kk++)
        bfr[kk] = *(const short8*)&o2[nl * 136 + kk * 32 + quad * 8];

    float4v acc[8];
    #pragma unroll
    for (int ot = 0; ot < 8; ot++) {
        acc[ot] = zero;
        const unsigned short* wp = wo + (ot * 16 + l15) * C_ + quad * 8;
        #pragma unroll
        for (int kk = 0; kk < 4; kk++) {
            short8 a = *(const short8*)(wp + kk * 32);
            acc[ot] = __builtin_amdgcn_mfma_f32_16x16x32_bf16(a, bfr[kk], acc[ot], 0, 0, 0);
        }
    }

    // bias + LayerNorm over the 128 channels of this column
    float sum = 0.f, sq = 0.f;
    #pragma unroll
    for (int ot = 0; ot < 8; ot++) {
        #pragma unroll
        for (int r = 0; r < 4; r++) {
            const int o = ot * 16 + quad * 4 + r;
            const float y = acc[ot][r] + bout[o];
            acc[ot][r] = y;
            sum += y; sq += y * y;
        }
    }
    sum += __shfl_xor(sum, 16, 64);
    sum += __shfl_xor(sum, 32, 64);
    sq  += __shfl_xor(sq, 16, 64);
    sq  += __shfl_xor(sq, 32, 64);
    const float mean = sum * (1.0f / 128.0f);
    const float var  = sq * (1.0f / 128.0f) - mean * mean;   // biased, matches jnp.var
    const float rstd = rsqrtf(var + 1e-5f);

    #pragma unroll
    for (int ot = 0; ot < 8; ot++) {
        #pragma unroll
        for (int r = 0; r < 4; r++) {
            const int o = ot * 16 + quad * 4 + r;
            out[((size_t)b * C_ + o) * N_ + n] = (acc[ot][r] - mean) * rstd * lnw[o] + lnb[o];
        }
    }
}

extern "C" void kernel_launch(void* const* d_in, const int* in_sizes, int n_in,
                              void* d_out, int out_size, void* d_ws, size_t ws_size,
                              hipStream_t stream) {
    const float* x    = (const float*)d_in[0];
    const float* Wqkv = (const float*)d_in[1];
    const float* Wout = (const float*)d_in[2];
    const float* bout = (const float*)d_in[3];
    const float* lnw  = (const float*)d_in[4];
    const float* lnb  = (const float*)d_in[5];
    float* out = (float*)d_out;

    char* ws = (char*)d_ws;
    unsigned short* wq  = (unsigned short*)(ws + OFF_WQ);
    unsigned short* wo  = (unsigned short*)(ws + OFF_WO);
    float* S            = (float*)(ws + OFF_S);
    float* ctx          = (float*)(ws + OFF_CTX);
    unsigned short* qsm = (unsigned short*)(ws + OFF_QSM);

    k0_prep<<<512, 256, 0, stream>>>(Wqkv, Wout, wq, wo, S, ctx);
    k1_qkv<<<dim3(N_ / 64, B_), 512, 0, stream>>>(x, wq, qsm, ctx, S);
    k3_out<<<dim3(N_ / 64, B_), 256, 0, stream>>>(qsm, ctx, S, wo, bout, lnw, lnb, out);
}

// Round 2
// 302.880 us; speedup vs baseline: 1.6383x; 1.6383x over previous
//
#include <hip/hip_runtime.h>
#include <stdint.h>

// LinearAttention fused: qkv GEMM + dual softmax + linear attention + Wout GEMM + LayerNorm2d
// Shapes: b=32, c=128, n=64*64=4096, heads=4, dim_head=32.
// All GEMMs via v_mfma_f32_16x16x32_bf16 (fp32 accum). Softmaxes computed without
// max-subtraction (qkv values ~N(0,1), exp range safe in fp32).
//
// R2: atomic-free. Round-1 k1 spent ~395us spinning in fp32 atomicAdd CAS loops
// (all pipes <5% busy). Now each k1 block covers 256 n (4 subtiles), holds its
// context tile in registers, writes plain partials; k2 reduces partials + 1/S
// and emits context in bf16 A-frag layout for k3.

constexpr int B_   = 32;
constexpr int C_   = 128;
constexpr int N_   = 4096;
constexpr int H_   = 4;
constexpr int O3_  = 384;   // 3*128 qkv rows
constexpr int NSUB = 4;     // 64-wide n-subtiles per k1 block
constexpr int TPB_ = 16;    // k1 blocks per batch (4096 / 256)

using short8  = __attribute__((ext_vector_type(8))) short;
using short4v = __attribute__((ext_vector_type(4))) short;
using float4v = __attribute__((ext_vector_type(4))) float;

__device__ __forceinline__ unsigned short bf16_rne(float f) {
    union { float f; uint32_t u; } v; v.f = f;
    uint32_t u = v.u;
    u += 0x7FFFu + ((u >> 16) & 1u);   // round-to-nearest-even
    return (unsigned short)(u >> 16);
}
__device__ __forceinline__ float bf2f(unsigned short h) {
    union { uint32_t u; float f; } v; v.u = ((uint32_t)h) << 16; return v.f;
}

// workspace layout (bytes)
constexpr size_t OFF_WQ   = 0;          // Wqkv bf16: 384*128*2 = 98304
constexpr size_t OFF_WO   = 98304;      // Wout bf16: 128*128*2 = 32768
constexpr size_t OFF_SP   = 131072;     // S partials [b][16][128] f32: 262144
constexpr size_t OFF_CTXP = 393216;     // ctx partials [b][16][4096] f32: 8388608
constexpr size_t OFF_CTXN = 8781824;    // ctx normalized bf16 [b][h*32+e][d]: 262144
constexpr size_t OFF_QSM  = 9043968;    // q-softmax bf16 [b][n][h*32+d]: 33554432
// total 42,598,400 bytes

__global__ __launch_bounds__(256) void k0_prep(const float* __restrict__ Wqkv,
                                               const float* __restrict__ Wout,
                                               unsigned short* __restrict__ wq,
                                               unsigned short* __restrict__ wo) {
    int t = blockIdx.x * 256 + threadIdx.x;      // grid = 192*256 = 49152
    if (t < O3_ * C_) wq[t] = bf16_rne(Wqkv[t]);
    if (t < C_ * C_)  wo[t] = bf16_rne(Wout[t]);
}

// K1: per (b, 256-wide n-tile): for each 64-subtile: qkv = Wqkv @ x, q-softmax -> qsm,
// exp(k), v -> LDS, context accumulated in registers (MFMA). Partials to global at end.
__global__ __launch_bounds__(512) void k1_qkv(const float* __restrict__ x,
                                              const unsigned short* __restrict__ wq,
                                              unsigned short* __restrict__ qsm,
                                              float* __restrict__ ctx_part,
                                              float* __restrict__ S_part) {
    __shared__ __align__(16) unsigned short xs[64 * 136];    // [n][c], stride 136
    __shared__ __align__(16) unsigned short ek[128 * 72];    // [h*32+d][n], stride 72
    __shared__ __align__(16) unsigned short vsh[128 * 72];   // [h*32+e][n]

    const int b    = blockIdx.y;
    const int tblk = blockIdx.x;                 // 0..15
    const int tid  = threadIdx.x;

    const int lane = tid & 63;
    const int wv   = tid >> 6;                   // 0..7
    const int l15  = lane & 15;
    const int quad = lane >> 4;
    const int cw   = wv & 3;                     // n col-tile within the 64
    const int ncol = cw * 16 + l15;
    const int rp0  = (wv >> 2) * 6;              // waves 0-3: row-pairs 0..5; 4-7: 6..11

    const float4v zero = {0.f, 0.f, 0.f, 0.f};
    float4v cacc[2] = {zero, zero};              // this wave's 2 context tiles
    float s_acc = 0.f;                           // this thread's S partial

    for (int s = 0; s < NSUB; s++) {
        const int ns = (tblk * NSUB + s) * 64;
        __syncthreads();                         // protect xs/ek/vsh from prev readers

        {   // stage x (fp32 global, coalesced along n) -> bf16 LDS [n][c]
            const int nl = tid & 63;
            const int cg = tid >> 6;             // 8 groups of 16 c
            const float* xp = x + ((size_t)b * C_ + (size_t)cg * 16) * N_ + ns + nl;
            unsigned short* dst = &xs[nl * 136 + cg * 16];
            #pragma unroll
            for (int i = 0; i < 2; i++) {
                short8 v8;
                #pragma unroll
                for (int j = 0; j < 8; j++)
                    v8[j] = (short)bf16_rne(xp[(size_t)(i * 8 + j) * N_]);
                *(short8*)(dst + i * 8) = v8;
            }
        }
        __syncthreads();

        // B-frags (x) loaded once, reused for all 12 row-pairs: B[k=c][col=n]
        short8 bfx[4];
        #pragma unroll
        for (int kk = 0; kk < 4; kk++)
            bfx[kk] = *(const short8*)&xs[ncol * 136 + kk * 32 + quad * 8];

        for (int rp = rp0; rp < rp0 + 6; rp++) {
            const unsigned short* wqp = wq + (rp * 32 + l15) * C_ + quad * 8;
            float4v acc0 = zero, acc1 = zero;
            #pragma unroll
            for (int kk = 0; kk < 4; kk++) {
                short8 a0 = *(const short8*)(wqp + kk * 32);
                short8 a1 = *(const short8*)(wqp + 16 * C_ + kk * 32);
                acc0 = __builtin_amdgcn_mfma_f32_16x16x32_bf16(a0, bfx[kk], acc0, 0, 0, 0);
                acc1 = __builtin_amdgcn_mfma_f32_16x16x32_bf16(a1, bfx[kk], acc1, 0, 0, 0);
            }
            // C/D layout: col = l15 (n), row = quad*4 + r (acc0: d 0..15, acc1: d 16..31)
            if (rp < 4) {
                // q rows, head h = rp: softmax over d (32) per column
                float e0[4], e1[4];
                float z = 0.f;
                #pragma unroll
                for (int r = 0; r < 4; r++) {
                    e0[r] = __expf(acc0[r]); e1[r] = __expf(acc1[r]);
                    z += e0[r] + e1[r];
                }
                z += __shfl_xor(z, 16, 64);
                z += __shfl_xor(z, 32, 64);
                const float iz = 1.0f / z;
                unsigned short* qp = qsm + ((size_t)b * N_ + ns + ncol) * C_ + rp * 32 + quad * 4;
                short4v s0, s1;
                #pragma unroll
                for (int r = 0; r < 4; r++) {
                    s0[r] = (short)bf16_rne(e0[r] * iz);
                    s1[r] = (short)bf16_rne(e1[r] * iz);
                }
                *(short4v*)qp = s0;              // d = quad*4..+3
                *(short4v*)(qp + 16) = s1;       // d = 16+quad*4..+3
            } else if (rp < 8) {
                // k rows, head h = rp-4: exp -> LDS [h*32+d][n]
                const int row0 = (rp - 4) * 32 + quad * 4;
                #pragma unroll
                for (int r = 0; r < 4; r++) {
                    ek[(row0 + r) * 72 + ncol]      = bf16_rne(__expf(acc0[r]));
                    ek[(row0 + 16 + r) * 72 + ncol] = bf16_rne(__expf(acc1[r]));
                }
            } else {
                // v rows, head h = rp-8 -> LDS [h*32+e][n]
                const int row0 = (rp - 8) * 32 + quad * 4;
                #pragma unroll
                for (int r = 0; r < 4; r++) {
                    vsh[(row0 + r) * 72 + ncol]      = bf16_rne(acc0[r]);
                    vsh[(row0 + 16 + r) * 72 + ncol] = bf16_rne(acc1[r]);
                }
            }
        }
        __syncthreads();

        // context: cacc[d][e] += sum_n expk[d][n] * v[e][n]  (MFMA, K = 64)
        #pragma unroll
        for (int i = 0; i < 2; i++) {
            const int t = wv * 2 + i;            // 16 tiles: (h, d-tile, e-tile)
            const int h = t >> 2, dt = (t >> 1) & 1, et = t & 1;
            const unsigned short* ap = &ek[(h * 32 + dt * 16 + l15) * 72 + quad * 8];
            const unsigned short* bp = &vsh[(h * 32 + et * 16 + l15) * 72 + quad * 8];
            #pragma unroll
            for (int kk = 0; kk < 2; kk++) {
                short8 a  = *(const short8*)(ap + kk * 32);
                short8 bb = *(const short8*)(bp + kk * 32);
                cacc[i] = __builtin_amdgcn_mfma_f32_16x16x32_bf16(a, bb, cacc[i], 0, 0, 0);
            }
        }

        {   // S partial sums (same bf16 values the context MFMA consumed)
            const int row = tid >> 2;            // 0..127 = h*32+d
            const int sub = tid & 3;
            const unsigned short* ep = &ek[row * 72 + sub * 16];
            float ss = 0.f;
            #pragma unroll
            for (int j = 0; j < 16; j++) ss += bf2f(ep[j]);
            s_acc += ss;
        }
    }

    // write-out: plain stores, no atomics
    float* cp_base = ctx_part + ((size_t)(b * TPB_ + tblk) << 12);
    #pragma unroll
    for (int i = 0; i < 2; i++) {
        const int t = wv * 2 + i;
        const int h = t >> 2, dt = (t >> 1) & 1, et = t & 1;
        float* cp = cp_base + ((h * 32 + dt * 16 + quad * 4) * 32 + et * 16 + l15);
        #pragma unroll
        for (int r = 0; r < 4; r++) cp[r * 32] = cacc[i][r];
    }
    {
        float ss = s_acc;
        ss += __shfl_xor(ss, 1, 64);
        ss += __shfl_xor(ss, 2, 64);
        if ((tid & 3) == 0)
            S_part[(size_t)(b * TPB_ + tblk) * 128 + (tid >> 2)] = ss;
    }
}

// K2: reduce 16 partials per b, fold 1/S, emit bf16 context in A-frag layout [b][h*32+e][d]
__global__ __launch_bounds__(256) void k2_reduce(const float* __restrict__ ctx_part,
                                                 const float* __restrict__ S_part,
                                                 unsigned short* __restrict__ ctxn) {
    __shared__ float Sinv[128];
    const int b = blockIdx.x;
    const int tid = threadIdx.x;
    if (tid < 128) {
        float s = 0.f;
        #pragma unroll
        for (int t = 0; t < TPB_; t++)
            s += S_part[(size_t)(b * TPB_ + t) * 128 + tid];
        Sinv[tid] = 1.0f / s;
    }
    __syncthreads();
    #pragma unroll
    for (int j = 0; j < 16; j++) {
        const int ei = j * 256 + tid;            // flat [h][d][e]
        float v = 0.f;
        #pragma unroll
        for (int t = 0; t < TPB_; t++)
            v += ctx_part[((size_t)(b * TPB_ + t) << 12) + ei];
        const int h = ei >> 10, d = (ei >> 5) & 31, e = ei & 31;
        ctxn[(size_t)b * 4096 + (h * 32 + e) * 32 + d] = bf16_rne(v * Sinv[h * 32 + d]);
    }
}

// K3: out2 = ctxn @ qsm per head (K=32), y = Wout @ out2 + bout (K=128), LayerNorm over c.
__global__ __launch_bounds__(256) void k3_out(const unsigned short* __restrict__ qsm,
                                              const unsigned short* __restrict__ ctxn,
                                              const unsigned short* __restrict__ wo,
                                              const float* __restrict__ bout,
                                              const float* __restrict__ lnw,
                                              const float* __restrict__ lnb,
                                              float* __restrict__ out) {
    __shared__ __align__(16) unsigned short o2[64 * 136];    // [n][h*32+e], stride 136

    const int b  = blockIdx.y;
    const int n0 = blockIdx.x * 64;
    const int tid = threadIdx.x;

    const int lane = tid & 63, wv = tid >> 6, l15 = lane & 15, quad = lane >> 4;
    const int nl = wv * 16 + l15;
    const size_t n = (size_t)n0 + nl;

    const float4v zero = {0.f, 0.f, 0.f, 0.f};
    #pragma unroll
    for (int h = 0; h < 4; h++) {
        // B-frag: qsm[d][n], d contiguous in global layout [b][n][h*32+d]
        short8 bq = *(const short8*)(qsm + ((size_t)b * N_ + n) * C_ + h * 32 + quad * 8);
        #pragma unroll
        for (int et = 0; et < 2; et++) {
            // A-frag straight from ctxn (already [h*32+e][d] per b)
            short8 a = *(const short8*)(ctxn + (size_t)b * 4096 + (h * 32 + et * 16 + l15) * 32 + quad * 8);
            float4v c4 = __builtin_amdgcn_mfma_f32_16x16x32_bf16(a, bq, zero, 0, 0, 0);
            short4v s4;
            #pragma unroll
            for (int r = 0; r < 4; r++) s4[r] = (short)bf16_rne(c4[r]);
            *(short4v*)&o2[nl * 136 + h * 32 + et * 16 + quad * 4] = s4;
        }
    }
    __syncthreads();

    short8 bfr[4];                               // B-frags (out2) reused across 8 o-tiles
    #pragma unroll
    for (int kk = 0; kk < 4; kk++)
        bfr[kk] = *(const short8*)&o2[nl * 136 + kk * 32 + quad * 8];

    float4v acc[8];
    #pragma unroll
    for (int ot = 0; ot < 8; ot++) {
        acc[ot] = zero;
        const unsigned short* wp = wo + (ot * 16 + l15) * C_ + quad * 8;
        #pragma unroll
        for (int kk = 0; kk < 4; kk++) {
            short8 a = *(const short8*)(wp + kk * 32);
            acc[ot] = __builtin_amdgcn_mfma_f32_16x16x32_bf16(a, bfr[kk], acc[ot], 0, 0, 0);
        }
    }

    // bias + LayerNorm over the 128 channels of this column
    float sum = 0.f, sq = 0.f;
    #pragma unroll
    for (int ot = 0; ot < 8; ot++) {
        #pragma unroll
        for (int r = 0; r < 4; r++) {
            const int o = ot * 16 + quad * 4 + r;
            const float y = acc[ot][r] + bout[o];
            acc[ot][r] = y;
            sum += y; sq += y * y;
        }
    }
    sum += __shfl_xor(sum, 16, 64);
    sum += __shfl_xor(sum, 32, 64);
    sq  += __shfl_xor(sq, 16, 64);
    sq  += __shfl_xor(sq, 32, 64);
    const float mean = sum * (1.0f / 128.0f);
    const float var  = sq * (1.0f / 128.0f) - mean * mean;   // biased, matches jnp.var
    const float rstd = rsqrtf(var + 1e-5f);

    #pragma unroll
    for (int ot = 0; ot < 8; ot++) {
        #pragma unroll
        for (int r = 0; r < 4; r++) {
            const int o = ot * 16 + quad * 4 + r;
            out[((size_t)b * C_ + o) * N_ + n] = (acc[ot][r] - mean) * rstd * lnw[o] + lnb[o];
        }
    }
}

extern "C" void kernel_launch(void* const* d_in, const int* in_sizes, int n_in,
                              void* d_out, int out_size, void* d_ws, size_t ws_size,
                              hipStream_t stream) {
    const float* x    = (const float*)d_in[0];
    const float* Wqkv = (const float*)d_in[1];
    const float* Wout = (const float*)d_in[2];
    const float* bout = (const float*)d_in[3];
    const float* lnw  = (const float*)d_in[4];
    const float* lnb  = (const float*)d_in[5];
    float* out = (float*)d_out;

    char* ws = (char*)d_ws;
    unsigned short* wq   = (unsigned short*)(ws + OFF_WQ);
    unsigned short* wo   = (unsigned short*)(ws + OFF_WO);
    float* S_part        = (float*)(ws + OFF_SP);
    float* ctx_part      = (float*)(ws + OFF_CTXP);
    unsigned short* ctxn = (unsigned short*)(ws + OFF_CTXN);
    unsigned short* qsm  = (unsigned short*)(ws + OFF_QSM);

    k0_prep<<<192, 256, 0, stream>>>(Wqkv, Wout, wq, wo);
    k1_qkv<<<dim3(TPB_, B_), 512, 0, stream>>>(x, wq, qsm, ctx_part, S_part);
    k2_reduce<<<B_, 256, 0, stream>>>(ctx_part, S_part, ctxn);
    k3_out<<<dim3(N_ / 64, B_), 256, 0, stream>>>(qsm, ctxn, wo, bout, lnw, lnb, out);
}